// Round 4
// baseline (2652.648 us; speedup 1.0000x reference)
//
#include <hip/hip_runtime.h>

// EMA codebook update (VQ-VAE), MI355X. fp16-MFMA distance filter + exact
// fp32 rescore for near-ties. N=32768, K=8192, D=256.
// R4: fix A-swizzle carry bug (XOR after full offset) + cross-wave top2 merge.

#define DECAY 0.99f
#define OMD 0.01f
#define EPS 1e-5f
#define DELTA 0.5f

constexpr int N = 32768, K = 8192, D = 256;
constexpr int KSPLIT = 2;               // gemm grid: 128 row-tiles x 2 code-splits
constexpr int BMt = 256, BNt = 128;     // gemm tile
constexpr int GT = 512;                 // gemm threads (8 waves)

typedef _Float16 f16x8 __attribute__((ext_vector_type(8)));
typedef float f32x4 __attribute__((ext_vector_type(4)));

// d_out layout (floats, reference return order)
constexpr long Q_OFF   = 0;
constexpr long IDX_OFF = (long)N * D;
constexpr long CB_OFF  = IDX_OFF + N;
constexpr long EMB_OFF = CB_OFF + (long)K * D;
constexpr long CS_OFF  = EMB_OFF + (long)K * D;

// ws layout (bytes)
constexpr long WS_TOPS = 0;                          // ulonglong2[N*KSPLIT]
constexpr long WS_RES  = WS_TOPS + (long)N * 2 * 16; // u64[N] resolved
constexpr long WS_IDX  = WS_RES + (long)N * 8;       // int[N]
constexpr long WS_C2   = WS_IDX + (long)N * 4;       // float[K]
constexpr long WS_FLAG = WS_C2 + (long)K * 4;        // int[N] flagged rows
constexpr long WS_CNT  = WS_FLAG + (long)N * 4;      // [0] u32 count, [1] f32 nacc

__device__ inline unsigned transScore(float s) {
    unsigned u = __float_as_uint(s);
    return u ^ ((unsigned)((int)u >> 31) | 0x80000000u);   // order-preserving
}
__device__ inline float untransScore(unsigned u) {
    return (u & 0x80000000u) ? __uint_as_float(u ^ 0x80000000u)
                             : __uint_as_float(~u);
}

__global__ void init_kernel(const float* __restrict__ emb_avg,
                            const float* __restrict__ cs,
                            float* __restrict__ out, char* __restrict__ ws) {
    int i = blockIdx.x * blockDim.x + threadIdx.x;   // grid covers K*D/4
    const float4* e4 = (const float4*)emb_avg;
    float4* o4 = (float4*)(out + EMB_OFF);
    if (i < K * D / 4) {
        float4 v = e4[i];
        v.x *= DECAY; v.y *= DECAY; v.z *= DECAY; v.w *= DECAY;
        o4[i] = v;
    }
    if (i < K) out[CS_OFF + i] = cs[i] * DECAY;
    if (i < N) ((unsigned long long*)(ws + WS_RES))[i] = ~0ull;
    if (i == 0) {
        ((unsigned*)(ws + WS_CNT))[0] = 0u;
        ((float*)(ws + WS_CNT))[1] = 0.f;
    }
}

__global__ void c2_kernel(const float* __restrict__ cb, float* __restrict__ c2) {
    int k = blockIdx.x;
    int lane = threadIdx.x;
    const float4* row = (const float4*)(cb + (long)k * D);
    float4 v = row[lane];
    float s = v.x * v.x + v.y * v.y + v.z * v.z + v.w * v.w;
    for (int off = 32; off; off >>= 1) s += __shfl_xor(s, off);
    if (lane == 0) c2[k] = s;
}

// ---------------- fp16 MFMA distance GEMM with top-2 tracking ----------------
__global__ __launch_bounds__(GT, 2) void gemm_kernel(
        const float* __restrict__ z, const float* __restrict__ cb,
        const float* __restrict__ c2, ulonglong2* __restrict__ tops) {
    __shared__ _Float16 As[BMt * 256];          // 128 KB, swizzled
    __shared__ _Float16 Bs[2][BNt * 32];        // 2 x 8 KB, swizzled
    __shared__ float c2s[BNt];
    __shared__ unsigned long long L1[BMt];      // block-level top1 (score|idx)
    __shared__ unsigned L2s[BMt];               // block-level top2 score

    const int tid = threadIdx.x;
    const int lane = tid & 63;
    const int wave = tid >> 6;                  // 8 waves: 4(M) x 2(N)
    const int wm = wave >> 1, wn = wave & 1;
    const long rowBase = (long)blockIdx.x * BMt;
    const int kbase = blockIdx.y * (K / KSPLIT);

    // ---- stage A (z rows) once: fp32 -> fp16, swizzled ----
    for (int i = 0; i < 16; ++i) {
        int id = tid + i * GT;                  // 8192 chunks of 8 floats
        int r = id >> 5, dseg = (id & 31) * 8;
        const float4* src = (const float4*)(z + (rowBase + r) * D + dseg);
        float4 v0 = src[0], v1 = src[1];
        union { _Float16 h[8]; ulonglong2 u; } t;
        t.h[0] = (_Float16)v0.x; t.h[1] = (_Float16)v0.y;
        t.h[2] = (_Float16)v0.z; t.h[3] = (_Float16)v0.w;
        t.h[4] = (_Float16)v1.x; t.h[5] = (_Float16)v1.y;
        t.h[6] = (_Float16)v1.z; t.h[7] = (_Float16)v1.w;
        int byte = (r * 256 + dseg) * 2;
        byte ^= (r & 7) << 4;
        *(ulonglong2*)((char*)As + byte) = t.u;
    }
    // stage B chunk 0
    {
        int c = tid >> 2, dseg = (tid & 3) * 8;
        const float* s = cb + (long)(kbase + c) * D + dseg;
        float4 b0 = *(const float4*)s, b1 = *((const float4*)s + 1);
        union { _Float16 h[8]; ulonglong2 u; } t;
        t.h[0] = (_Float16)b0.x; t.h[1] = (_Float16)b0.y;
        t.h[2] = (_Float16)b0.z; t.h[3] = (_Float16)b0.w;
        t.h[4] = (_Float16)b1.x; t.h[5] = (_Float16)b1.y;
        t.h[6] = (_Float16)b1.z; t.h[7] = (_Float16)b1.w;
        int byte = (c * 32 + dseg) * 2;
        byte ^= (c & 7) << 4;
        *(ulonglong2*)((char*)&Bs[0][0] + byte) = t.u;
    }
    if (tid < BNt) c2s[tid] = c2[kbase + tid];
    if (tid < BMt) { L1[tid] = ~0ull; L2s[tid] = 0xFFFFFFFFu; }
    __syncthreads();

    // per-thread A/B frag byte offsets. A: base WITHOUT swizzle (dc added per
    // read, THEN xor — xor-after-add, see rule #21 / R3 carry bug).
    int aBase[4], aSwz[4], bOff[4];
#pragma unroll
    for (int fr = 0; fr < 4; ++fr) {
        int r = wm * 64 + fr * 16 + (lane & 15);
        aBase[fr] = r * 512 + (lane >> 4) * 16;
        aSwz[fr] = (r & 7) << 4;
    }
#pragma unroll
    for (int fc = 0; fc < 4; ++fc) {
        int c = wn * 64 + fc * 16 + (lane & 15);
        int byte = c * 64 + (lane >> 4) * 16;
        bOff[fc] = byte ^ ((c & 7) << 4);
    }

    f32x4 acc[4][4];
    unsigned long long t1[16];
    unsigned t2[16];
#pragma unroll
    for (int s = 0; s < 16; ++s) { t1[s] = ~0ull; t2[s] = 0xFFFFFFFFu; }
    float c2v[4];

    const int NCH = (K / KSPLIT / BNt) * 8;      // 256 chunks
    for (int j = 0; j < NCH; ++j) {
        const int kb = j >> 3, dcI = j & 7, dc = dcI * 32;
        const int cur = j & 1;
        // prefetch next chunk (global -> regs)
        float4 p0, p1;
        const bool pf = (j + 1 < NCH);
        if (pf) {
            int jj = j + 1;
            int c = tid >> 2, dseg = (tid & 3) * 8;
            const float* s = cb + (long)(kbase + (jj >> 3) * BNt + c) * D
                             + (jj & 7) * 32 + dseg;
            p0 = *(const float4*)s; p1 = *((const float4*)s + 1);
        }
        // compute current chunk
        if (dcI == 0) {
#pragma unroll
            for (int a = 0; a < 4; ++a)
#pragma unroll
                for (int b = 0; b < 4; ++b) acc[a][b] = (f32x4)0.f;
#pragma unroll
            for (int fc = 0; fc < 4; ++fc)
                c2v[fc] = c2s[wn * 64 + fc * 16 + (lane & 15)];
        }
        f16x8 aF[4], bF[4];
#pragma unroll
        for (int fr = 0; fr < 4; ++fr)
            aF[fr] = *(const f16x8*)((const char*)As +
                        ((aBase[fr] + dc * 2) ^ aSwz[fr]));
#pragma unroll
        for (int fc = 0; fc < 4; ++fc)
            bF[fc] = *(const f16x8*)((const char*)&Bs[cur][0] + bOff[fc]);
#pragma unroll
        for (int fr = 0; fr < 4; ++fr)
#pragma unroll
            for (int fc = 0; fc < 4; ++fc)
                acc[fr][fc] = __builtin_amdgcn_mfma_f32_16x16x32_f16(
                    aF[fr], bF[fc], acc[fr][fc], 0, 0, 0);
        if (dcI == 7) {
            // score + top2 update
#pragma unroll
            for (int fc = 0; fc < 4; ++fc) {
                int gcol = kbase + kb * BNt + wn * 64 + fc * 16 + (lane & 15);
#pragma unroll
                for (int fr = 0; fr < 4; ++fr)
#pragma unroll
                    for (int r = 0; r < 4; ++r) {
                        float s = fmaf(-2.f, acc[fr][fc][r], c2v[fc]);
                        unsigned su = transScore(s);
                        unsigned long long u =
                            ((unsigned long long)su << 32) | (unsigned)gcol;
                        int slot = fr * 4 + r;
                        unsigned old1 = (unsigned)(t1[slot] >> 32);
                        t1[slot] = u < t1[slot] ? u : t1[slot];
                        unsigned mx = su > old1 ? su : old1;
                        t2[slot] = t2[slot] < mx ? t2[slot] : mx;
                    }
            }
        }
        __syncthreads();             // everyone done reading Bs[cur]/c2s
        if (pf) {
            int jj = j + 1;
            int c = tid >> 2, dseg = (tid & 3) * 8;
            union { _Float16 h[8]; ulonglong2 u; } t;
            t.h[0] = (_Float16)p0.x; t.h[1] = (_Float16)p0.y;
            t.h[2] = (_Float16)p0.z; t.h[3] = (_Float16)p0.w;
            t.h[4] = (_Float16)p1.x; t.h[5] = (_Float16)p1.y;
            t.h[6] = (_Float16)p1.z; t.h[7] = (_Float16)p1.w;
            int byte = (c * 32 + dseg) * 2;
            byte ^= (c & 7) << 4;
            *(ulonglong2*)((char*)&Bs[cur ^ 1][0] + byte) = t.u;
            if ((jj & 7) == 0 && tid < BNt)     // new kb: stage its c2
                c2s[tid] = c2[kbase + (jj >> 3) * BNt + tid];
        }
        __syncthreads();
    }

    // intra-wave top2 merge over the 16 lanes sharing each row
#pragma unroll
    for (int m = 1; m < 16; m <<= 1) {
#pragma unroll
        for (int s = 0; s < 16; ++s) {
            unsigned long long o1 = __shfl_xor(t1[s], m);
            unsigned o2 = (unsigned)__shfl_xor((int)t2[s], m);
            unsigned a1 = (unsigned)(t1[s] >> 32), b1 = (unsigned)(o1 >> 32);
            unsigned mx = a1 > b1 ? a1 : b1;
            unsigned nt2 = t2[s] < o2 ? t2[s] : o2;
            nt2 = nt2 < mx ? nt2 : mx;
            t1[s] = o1 < t1[s] ? o1 : t1[s];
            t2[s] = nt2;
        }
    }
    // cross-wave (wn=0/1) top2 merge via LDS atomicMin-displacement:
    // old = atomicMin(L1,t1); the loser max(t1,old) and own t2 both go to L2.
    if ((lane & 15) == 0) {
#pragma unroll
        for (int s = 0; s < 16; ++s) {
            int row = wm * 64 + (s >> 2) * 16 + (lane >> 4) * 4 + (s & 3);
            unsigned long long old1 = atomicMin(&L1[row], t1[s]);
            unsigned long long cand = t1[s] < old1 ? old1 : t1[s];
            atomicMin(&L2s[row], (unsigned)(cand >> 32));
            atomicMin(&L2s[row], t2[s]);
        }
    }
    __syncthreads();
    if (tid < BMt) {
        ulonglong2 v; v.x = L1[tid]; v.y = (unsigned long long)L2s[tid];
        tops[(rowBase + tid) * KSPLIT + blockIdx.y] = v;
    }
}

__global__ void merge_kernel(const ulonglong2* __restrict__ tops,
                             float* __restrict__ out, int* __restrict__ idxArr,
                             unsigned* __restrict__ flagCount,
                             int* __restrict__ flagRows) {
    int row = blockIdx.x * 256 + threadIdx.x;
    ulonglong2 a = tops[row * 2], b = tops[row * 2 + 1];
    unsigned long long t1 = a.x < b.x ? a.x : b.x;
    unsigned a1 = (unsigned)(a.x >> 32), b1 = (unsigned)(b.x >> 32);
    unsigned mx = a1 > b1 ? a1 : b1;
    unsigned t2 = (unsigned)a.y < (unsigned)b.y ? (unsigned)a.y : (unsigned)b.y;
    t2 = t2 < mx ? t2 : mx;
    float s1 = untransScore((unsigned)(t1 >> 32));
    float s2 = untransScore(t2);
    int idx = (int)(t1 & 0xFFFFFFFFull);
    idxArr[row] = idx;
    out[IDX_OFF + row] = (float)idx;
    if (s2 - s1 <= DELTA) {
        unsigned p = atomicAdd(flagCount, 1u);
        flagRows[p] = row;
    }
}

// exact fp32 rescore of flagged rows: block = (32-row group) x (256-code split)
__global__ __launch_bounds__(256) void resolve_kernel(
        const float* __restrict__ z, const float* __restrict__ cb,
        const float* __restrict__ c2, const unsigned* __restrict__ flagCount,
        const int* __restrict__ flagRows, unsigned long long* __restrict__ resolved) {
    __shared__ float zs[32][260];
    const int cnt = (int)*flagCount;
    const int tid = threadIdx.x;
    const int csplit = blockIdx.x & 31;             // 256 codes each
    for (int g = blockIdx.x >> 5; g * 32 < cnt; g += 32) {
        __syncthreads();
        // stage 32 flagged rows' z
        for (int i = 0; i < 8; ++i) {
            int id = tid + i * 256;                 // 2048 float4 slots
            int r = id >> 6, j = id & 63;
            int fi = g * 32 + r;
            int row = fi < cnt ? flagRows[fi] : flagRows[g * 32];
            float4 v = *(const float4*)(z + (long)row * D + j * 4);
            *(float4*)&zs[r][j * 4] = v;
        }
        __syncthreads();
        int r = tid >> 3, cl = tid & 7;
        int fi = g * 32 + r;
        unsigned long long best = ~0ull;
        for (int kk = 0; kk < 32; ++kk) {
            int k = csplit * 256 + kk * 8 + cl;
            const float4* crow = (const float4*)(cb + (long)k * D);
            float dot = 0.f;
#pragma unroll 16
            for (int j = 0; j < 64; ++j) {
                float4 c4 = crow[j];
                float4 z4 = *(const float4*)&zs[r][j * 4];
                dot = fmaf(z4.x, c4.x, dot);
                dot = fmaf(z4.y, c4.y, dot);
                dot = fmaf(z4.z, c4.z, dot);
                dot = fmaf(z4.w, c4.w, dot);
            }
            float s = fmaf(-2.f, dot, c2[k]);
            unsigned long long u =
                ((unsigned long long)transScore(s) << 32) | (unsigned)k;
            best = u < best ? u : best;
        }
        // merge the 8 code-lanes of this row (lanes differ in low 3 bits)
#pragma unroll
        for (int m = 1; m < 8; m <<= 1) {
            unsigned long long o = __shfl_xor(best, m);
            best = o < best ? o : best;
        }
        if (cl == 0 && fi < cnt) {
            int row = flagRows[fi];
            atomicMin(&resolved[row], best);
        }
    }
}

__global__ void writeback_kernel(const unsigned* __restrict__ flagCount,
                                 const int* __restrict__ flagRows,
                                 const unsigned long long* __restrict__ resolved,
                                 int* __restrict__ idxArr, float* __restrict__ out) {
    int i = blockIdx.x * 256 + threadIdx.x;
    if (i < (int)*flagCount) {
        int row = flagRows[i];
        int idx = (int)(resolved[row] & 0xFFFFFFFFull);
        idxArr[row] = idx;
        out[IDX_OFF + row] = (float)idx;
    }
}

__global__ __launch_bounds__(512) void epilogue_kernel(
        const float* __restrict__ z, const float* __restrict__ cb,
        const int* __restrict__ idxArr, float* __restrict__ out) {
    int tid = threadIdx.x;
    int r = tid >> 2, seg = tid & 3;
    int gRow = blockIdx.x * 128 + r;
    int code = idxArr[gRow];
    if (seg == 0) atomicAdd(&out[CS_OFF + code], OMD);
    const float4* cbv = (const float4*)(cb + (long)code * D + seg * 64);
    const float4* zv  = (const float4*)(z + (long)gRow * D + seg * 64);
    float4* qv = (float4*)(out + Q_OFF + (long)gRow * D + seg * 64);
    float*  er = out + EMB_OFF + (long)code * D + seg * 64;
#pragma unroll 4
    for (int i = 0; i < 16; ++i) {
        float4 cv = cbv[i];
        qv[i] = cv;
        float4 zt = zv[i];
        atomicAdd(&er[i * 4 + 0], OMD * zt.x);
        atomicAdd(&er[i * 4 + 1], OMD * zt.y);
        atomicAdd(&er[i * 4 + 2], OMD * zt.z);
        atomicAdd(&er[i * 4 + 3], OMD * zt.w);
    }
}

__global__ void reduce_n(const float* __restrict__ out_cs, float* __restrict__ nacc) {
    int i = blockIdx.x * 256 + threadIdx.x;
    float v = out_cs[i];
    for (int off = 32; off; off >>= 1) v += __shfl_xor(v, off);
    __shared__ float wsum[4];
    int lane = threadIdx.x & 63, w = threadIdx.x >> 6;
    if (lane == 0) wsum[w] = v;
    __syncthreads();
    if (threadIdx.x == 0) atomicAdd(nacc, wsum[0] + wsum[1] + wsum[2] + wsum[3]);
}

__global__ void finalize_kernel(const float* __restrict__ nacc, float* __restrict__ out) {
    int k = blockIdx.x, d = threadIdx.x;
    float n = *nacc;
    float ncs = out[CS_OFF + k];
    float smoothed = (ncs + EPS) / (n + (float)K * EPS) * n;
    out[CB_OFF + (long)k * D + d] = out[EMB_OFF + (long)k * D + d] / smoothed;
}

extern "C" void kernel_launch(void* const* d_in, const int* in_sizes, int n_in,
                              void* d_out, int out_size, void* d_ws, size_t ws_size,
                              hipStream_t stream) {
    const float* z   = (const float*)d_in[0];
    const float* cb  = (const float*)d_in[1];
    const float* emb = (const float*)d_in[2];
    const float* cs  = (const float*)d_in[3];
    float* out = (float*)d_out;
    char* ws = (char*)d_ws;

    ulonglong2* tops = (ulonglong2*)(ws + WS_TOPS);
    unsigned long long* resolved = (unsigned long long*)(ws + WS_RES);
    int* idxArr = (int*)(ws + WS_IDX);
    float* c2 = (float*)(ws + WS_C2);
    int* flagRows = (int*)(ws + WS_FLAG);
    unsigned* flagCount = (unsigned*)(ws + WS_CNT);
    float* nacc = (float*)(ws + WS_CNT) + 1;

    init_kernel<<<(K * D / 4 + 255) / 256, 256, 0, stream>>>(emb, cs, out, ws);
    c2_kernel<<<K, 64, 0, stream>>>(cb, c2);
    dim3 ggrid(N / BMt, KSPLIT);
    gemm_kernel<<<ggrid, GT, 0, stream>>>(z, cb, c2, tops);
    merge_kernel<<<N / 256, 256, 0, stream>>>(tops, out, idxArr, flagCount, flagRows);
    resolve_kernel<<<1024, 256, 0, stream>>>(z, cb, c2, flagCount, flagRows, resolved);
    writeback_kernel<<<N / 256, 256, 0, stream>>>(flagCount, flagRows, resolved, idxArr, out);
    epilogue_kernel<<<N / 128, 512, 0, stream>>>(z, cb, idxArr, out);
    reduce_n<<<K / 256, 256, 0, stream>>>(out + CS_OFF, nacc);
    finalize_kernel<<<K, 256, 0, stream>>>(nacc, out);
}